// Round 5
// baseline (270.412 us; speedup 1.0000x reference)
//
#include <hip/hip_runtime.h>
#include <hip/hip_fp16.h>
#include <hip/hip_cooperative_groups.h>
#include <math.h>

namespace cg = cooperative_groups;

// TriangleAttentionStartingNode: B=1, N=256, C=128, H=4, AC=32, fp32 in/out.
// R6: precision-lite pipeline (bf16 q/k/v/P, fp16 g, hi/lo split only on
//     the out-GEMM). absmax 6.1e-5.
// R7 FAILED: forced VGPR 64 -> spills. Occupancy proven not the lever.
// R8 WIN(+11%): zero-barrier lnproj, wave-private LDS planes.
// R9 FAILED: more waves, less per-wave work -> slower. ~60us/act-kernel law.
// R10 WIN(204->194): full fusion, mega=122.8us (FETCH 21.7MB WRITE 32.8MB,
//     VALU 21% MFMA 7% HBM 6% -> 75% of cycles nothing issues). nb_kernel
//     ~60us by subtraction — second act-streaming dispatch = pure tax.
// R11: cooperative launch. mega phase A also computes nb (block m LNs
//     exactly the rows nb[h,m,:] needs) -> write nbP -> grid.sync() ->
//     attention. nb_kernel deleted. Plus 1-deep nbP prefetch pipeline in
//     the jb loop (removes ~600cy L2/L3 latency x32 iters from the chain).

#define NRES 256
#define CCH  128
#define NROWS (NRES * NRES)          // 65536
#define FACTOR 0.17677669529663687f  // 1/sqrt(32)

typedef __attribute__((ext_vector_type(8))) __bf16 bf16x8;
typedef __attribute__((ext_vector_type(4))) float f32x4;

__device__ __forceinline__ f32x4 mfma16(bf16x8 a, bf16x8 b, f32x4 c) {
    return __builtin_amdgcn_mfma_f32_16x16x32_bf16(a, b, c, 0, 0, 0);
}

union PK4 { __bf16 b[4]; uint2 u2; };

__device__ __forceinline__ void hilo(float x, __bf16& h, __bf16& l) {
    h = (__bf16)x;
    l = (__bf16)(x - (float)h);
}

// ---------------- weight prep: pack into B-frag layout ----------------
__global__ __launch_bounds__(256) void prep_kernel(
    const float* __restrict__ wq, const float* __restrict__ wk,
    const float* __restrict__ wv, const float* __restrict__ wg,
    const float* __restrict__ wo,
    __bf16* __restrict__ wph, __bf16* __restrict__ wpl)
{
    const int gid = blockIdx.x * 256 + threadIdx.x;   // 0..10239
    const int wid = gid >> 11;
    const int rem = gid & 2047;
    const int nstrip = rem >> 8;
    const int kf = (rem >> 6) & 3;
    const int lane = rem & 63;
    const int l15 = lane & 15, quad = lane >> 4;
    const float* W = (wid == 0) ? wq : (wid == 1) ? wk :
                     (wid == 2) ? wv : (wid == 3) ? wg : wo;
    const float scale = (wid == 0) ? FACTOR : 1.0f;
    bf16x8 hb, lb;
    #pragma unroll
    for (int e = 0; e < 8; ++e) {
        int k = kf * 32 + quad * 8 + e;
        int n = nstrip * 16 + l15;
        float v = W[k * CCH + n] * scale;
        __bf16 h, l; hilo(v, h, l);
        hb[e] = h; lb[e] = l;
    }
    *(bf16x8*)&wph[(size_t)gid * 8] = hb;
    *(bf16x8*)&wpl[(size_t)gid * 8] = lb;
}

// ---------------- projection helper: 32 rows x 128 out-ch, single bf16 ----
__device__ __forceinline__ void proj32(const bf16x8* A0, const bf16x8* A1,
    const __bf16* __restrict__ Bh, int lane, f32x4* acc0, f32x4* acc1)
{
    #pragma unroll
    for (int n = 0; n < 8; ++n) {
        acc0[n] = (f32x4){0.f, 0.f, 0.f, 0.f};
        acc1[n] = (f32x4){0.f, 0.f, 0.f, 0.f};
    }
    #pragma unroll
    for (int kf = 0; kf < 4; ++kf)
        #pragma unroll
        for (int n = 0; n < 8; ++n) {
            bf16x8 bh = *(const bf16x8*)&Bh[(size_t)((n * 4 + kf) * 64 + lane) * 8];
            acc0[n] = mfma16(A0[kf], bh, acc0[n]);
            acc1[n] = mfma16(A1[kf], bh, acc1[n]);
        }
}

// ---------------- mega kernel (cooperative): LN+nb+proj | sync | attn+out --
// One block per pair-row m. 8 waves, wave w owns rows j in [w*32, w*32+32).
// LDS: [0)        K / wave planes: 8 x [32][136] bf16 = 69632 B (K[256][136])
//      [69632)    V^T [128][264] bf16                 = 67584 B
//      [137216)   p-buffers 8 x [16][40] bf16         = 10240 B
//      [147456)   biasrow [256] f32                   =  1024 B   tot 148480
__global__ __launch_bounds__(512) void mega_kernel(
    const float* __restrict__ act, const float* __restrict__ ln_g,
    const float* __restrict__ ln_b, const float* __restrict__ w2d,
    const __bf16* __restrict__ wph, const __bf16* __restrict__ wpl,
    const float* __restrict__ bg, const float* __restrict__ mask,
    float* __restrict__ nbP, const float* __restrict__ bo,
    float* __restrict__ out)
{
    __shared__ __align__(16) char smem[148480];
    const int t = threadIdx.x, w = t >> 6, lane = t & 63;
    const int l15 = lane & 15, quad = lane >> 4;
    const int m = blockIdx.x;
    __bf16* const Kl = (__bf16*)smem;                        // [256][136]
    __bf16* const aH = (__bf16*)(smem + w * 8704);           // plane w [32][136]
    __bf16* const VT = (__bf16*)(smem + 69632);              // [128][264]
    __bf16* const ph = (__bf16*)(smem + 137216 + w * 1280);  // [16][40]
    float*  const biasrow = (float*)(smem + 147456);         // [256]

    if (t < 256) biasrow[t] = 1e9f * (mask[m * NRES + t] - 1.0f);

    // ---- Phase A: LN of this wave's 32 rows -> aH, + nb -> nbP ----
    {
        const int row = lane >> 1, half = lane & 1;
        const int grow = m * NRES + w * 32 + row;
        const float* __restrict__ xp = act + (size_t)grow * CCH + half * 64;
        float4 x4[16];
        #pragma unroll
        for (int c = 0; c < 16; ++c) x4[c] = *(const float4*)(xp + c * 4);
        float s = 0.f, sq = 0.f;
        #pragma unroll
        for (int c = 0; c < 16; ++c) {
            s  += (x4[c].x + x4[c].y) + (x4[c].z + x4[c].w);
            sq += x4[c].x * x4[c].x + x4[c].y * x4[c].y +
                  x4[c].z * x4[c].z + x4[c].w * x4[c].w;
        }
        s  += __shfl_xor(s, 1, 64);
        sq += __shfl_xor(sq, 1, 64);
        float mu  = s * (1.0f / CCH);
        float var = fmaf(sq, 1.0f / CCH, -mu * mu);
        float rs  = rsqrtf(var + 1e-5f);
        float nb[4] = {0.f, 0.f, 0.f, 0.f};
        const float4* __restrict__ w2d4 = (const float4*)w2d;
        #pragma unroll
        for (int c2 = 0; c2 < 8; ++c2) {
            bf16x8 pk;
            #pragma unroll
            for (int cc = 0; cc < 2; ++cc) {
                const int c = c2 * 2 + cc;
                float4 g4 = *(const float4*)&ln_g[half * 64 + c * 4];
                float4 b4 = *(const float4*)&ln_b[half * 64 + c * 4];
                float* xv = (float*)&x4[c];
                float* gv = (float*)&g4;
                float* bv = (float*)&b4;
                #pragma unroll
                for (int e = 0; e < 4; ++e) {
                    float av = fmaf((xv[e] - mu) * rs, gv[e], bv[e]);
                    pk[cc * 4 + e] = (__bf16)av;
                    float4 wv = w2d4[half * 64 + c * 4 + e];
                    nb[0] = fmaf(av, wv.x, nb[0]);
                    nb[1] = fmaf(av, wv.y, nb[1]);
                    nb[2] = fmaf(av, wv.z, nb[2]);
                    nb[3] = fmaf(av, wv.w, nb[3]);
                }
            }
            *(bf16x8*)&aH[row * 136 + half * 64 + c2 * 8] = pk;
        }
        #pragma unroll
        for (int hh = 0; hh < 4; ++hh)
            nb[hh] += __shfl_xor(nb[hh], 1, 64);
        if (half == 0) {
            const int i = grow >> 8, j = grow & 255;
            #pragma unroll
            for (int hh = 0; hh < 4; ++hh) {
                size_t f = ((size_t)hh << 14) + ((size_t)(i >> 4) << 10) +
                           ((size_t)(j >> 4) << 6) + ((size_t)((j >> 2) & 3) << 4) +
                           (i & 15);
                nbP[f * 4 + (j & 3)] = nb[hh];
            }
        }
    }

    // ---- A-frags to regs (same-wave LDS dep). aH plane then recyclable.
    bf16x8 A0[4], A1[4];
    #pragma unroll
    for (int kf = 0; kf < 4; ++kf) {
        const int ao = l15 * 136 + kf * 32 + quad * 8;
        A0[kf] = *(const bf16x8*)&aH[ao];
        A1[kf] = *(const bf16x8*)&aH[ao + 16 * 136];
    }

    f32x4 acc0[8], acc1[8];
    bf16x8 Qh[4][2];          // [head][s]  B-frag of own q rows
    uint2  greg[4][2][2];     // [head][s][c] 4 fp16 gate vals

    // ---- q: project, restage through own plane, hoist B-frags ----
    proj32(A0, A1, wph, lane, acc0, acc1);
    {
        __bf16* const sth = aH;
        #pragma unroll
        for (int sp = 0; sp < 2; ++sp) {
            f32x4* accp = sp ? acc1 : acc0;
            #pragma unroll
            for (int n = 0; n < 8; ++n)
                #pragma unroll
                for (int r = 0; r < 4; ++r)
                    sth[(quad * 4 + r) * 136 + n * 16 + l15] = (__bf16)accp[n][r];
            #pragma unroll
            for (int h = 0; h < 4; ++h)
                Qh[h][sp] = *(const bf16x8*)&sth[l15 * 136 + h * 32 + quad * 8];
        }
    }

    // ---- g: project + bias + sigmoid (fp16), restage, hoist gate regs ----
    proj32(A0, A1, wph + 3 * 16384, lane, acc0, acc1);
    {
        __half* const sthH = (__half*)aH;
        #pragma unroll
        for (int sp = 0; sp < 2; ++sp) {
            f32x4* accp = sp ? acc1 : acc0;
            #pragma unroll
            for (int n = 0; n < 8; ++n)
                #pragma unroll
                for (int r = 0; r < 4; ++r) {
                    float v = accp[n][r] + bg[n * 16 + l15];
                    sthH[(quad * 4 + r) * 136 + n * 16 + l15] =
                        (__half)(1.0f / (1.0f + __expf(-v)));
                }
            #pragma unroll
            for (int h = 0; h < 4; ++h)
                #pragma unroll
                for (int c = 0; c < 2; ++c)
                    greg[h][sp][c] =
                        *(const uint2*)&sthH[l15 * 136 + h * 32 + c * 16 + quad * 4];
        }
    }

    // ---- k: project, write straight into own plane (= K rows) ----
    proj32(A0, A1, wph + 1 * 16384, lane, acc0, acc1);
    {
        __bf16* const Kp = aH;
        #pragma unroll
        for (int sp = 0; sp < 2; ++sp) {
            f32x4* accp = sp ? acc1 : acc0;
            #pragma unroll
            for (int n = 0; n < 8; ++n)
                #pragma unroll
                for (int r = 0; r < 4; ++r)
                    Kp[(sp * 16 + quad * 4 + r) * 136 + n * 16 + l15] =
                        (__bf16)accp[n][r];
        }
    }

    // ---- v: project, scatter into V^T ----
    proj32(A0, A1, wph + 2 * 16384, lane, acc0, acc1);
    {
        const int jbase = w * 32;
        #pragma unroll
        for (int sp = 0; sp < 2; ++sp) {
            f32x4* accp = sp ? acc1 : acc0;
            #pragma unroll
            for (int n = 0; n < 8; ++n)
                #pragma unroll
                for (int r = 0; r < 4; ++r)
                    VT[(n * 16 + l15) * 264 + jbase + sp * 16 + quad * 4 + r] =
                        (__bf16)accp[n][r];
        }
    }
    __syncthreads();          // block: K/VT ready
    __threadfence();          // nbP stores visible device-wide
    cg::this_grid().sync();   // all blocks' nbP written

    // ---- attention: 4 heads, own 32 q-rows, sweep all 256 j ----
    uint2 ovh[4][2][2], ovl[4][2][2];
    #pragma unroll
    for (int h = 0; h < 4; ++h) {
        f32x4 O[2][2];
        float ls[2] = {0.f, 0.f};
        #pragma unroll
        for (int s = 0; s < 2; ++s) {
            O[s][0] = (f32x4){0.f, 0.f, 0.f, 0.f};
            O[s][1] = (f32x4){0.f, 0.f, 0.f, 0.f};
        }
        // 1-deep nbP prefetch pipeline (static-indexed)
        float4 nb_a[2][2], nb_b[2][2];
        #pragma unroll
        for (int s = 0; s < 2; ++s)
            #pragma unroll
            for (int js = 0; js < 2; ++js)
                nb_a[s][js] = *(const float4*)&nbP[
                    ((size_t)h * 16384 + (size_t)(w * 2 + s) * 1024 +
                     (size_t)js * 64 + quad * 16 + l15) * 4];
        #pragma unroll 1
        for (int jb = 0; jb < NRES; jb += 32) {
            bf16x8 Kh[2];
            #pragma unroll
            for (int js = 0; js < 2; ++js)
                Kh[js] = *(const bf16x8*)&Kl[(jb + js * 16 + l15) * 136 +
                                             h * 32 + quad * 8];
            bf16x8 Vh2[2];
            #pragma unroll
            for (int c = 0; c < 2; ++c)
                Vh2[c] = *(const bf16x8*)&VT[(h * 32 + c * 16 + l15) * 264 +
                                             jb + quad * 8];
            // prefetch next iteration's nb (last iter: re-read tile 0, unused)
            const int jn = (jb + 32 < NRES) ? (jb >> 4) + 2 : 0;
            #pragma unroll
            for (int s = 0; s < 2; ++s)
                #pragma unroll
                for (int js = 0; js < 2; ++js)
                    nb_b[s][js] = *(const float4*)&nbP[
                        ((size_t)h * 16384 + (size_t)(w * 2 + s) * 1024 +
                         (size_t)(jn + js) * 64 + quad * 16 + l15) * 4];
            #pragma unroll
            for (int s = 0; s < 2; ++s) {
                #pragma unroll
                for (int js = 0; js < 2; ++js) {
                    f32x4 S = (f32x4){0.f, 0.f, 0.f, 0.f};
                    S = mfma16(Kh[js], Qh[h][s], S);
                    float4 nb4 = nb_a[s][js];
                    float4 mb4 = *(const float4*)&biasrow[jb + js * 16 + quad * 4];
                    float p0 = __expf(S[0] + nb4.x + mb4.x - 4.0f);
                    float p1 = __expf(S[1] + nb4.y + mb4.y - 4.0f);
                    float p2 = __expf(S[2] + nb4.z + mb4.z - 4.0f);
                    float p3 = __expf(S[3] + nb4.w + mb4.w - 4.0f);
                    ls[s] += (p0 + p1) + (p2 + p3);
                    PK4 hh;
                    hh.b[0] = (__bf16)p0; hh.b[1] = (__bf16)p1;
                    hh.b[2] = (__bf16)p2; hh.b[3] = (__bf16)p3;
                    *(uint2*)&ph[l15 * 40 + js * 16 + quad * 4] = hh.u2;
                }
                bf16x8 Ph = *(const bf16x8*)&ph[l15 * 40 + quad * 8];
                #pragma unroll
                for (int c = 0; c < 2; ++c)
                    O[s][c] = mfma16(Vh2[c], Ph, O[s][c]);
            }
            #pragma unroll
            for (int s = 0; s < 2; ++s)
                #pragma unroll
                for (int js = 0; js < 2; ++js)
                    nb_a[s][js] = nb_b[s][js];
        }
        #pragma unroll
        for (int s = 0; s < 2; ++s) {
            ls[s] += __shfl_xor(ls[s], 16, 64);
            ls[s] += __shfl_xor(ls[s], 32, 64);
        }
        // gate + normalize + hi/lo pack (regs only)
        #pragma unroll
        for (int s = 0; s < 2; ++s) {
            float inv = 1.0f / ls[s];
            #pragma unroll
            for (int c = 0; c < 2; ++c) {
                const __half* gh = (const __half*)&greg[h][s][c];
                PK4 hh, lo;
                #pragma unroll
                for (int r = 0; r < 4; ++r) {
                    float v = O[s][c][r] * inv * (float)gh[r];
                    __bf16 hb; __bf16 lb; hilo(v, hb, lb);
                    hh.b[r] = hb; lo.b[r] = lb;
                }
                ovh[h][s][c] = hh.u2;
                ovl[h][s][c] = lo.u2;
            }
        }
    }
    __syncthreads();   // K/VT/p dead for all waves

    // ---- out GEMM: restage hi/lo through own plane, 3-term split MFMA ----
    {
        __bf16* const sth = aH;
        #pragma unroll
        for (int h = 0; h < 4; ++h)
            #pragma unroll
            for (int s = 0; s < 2; ++s)
                #pragma unroll
                for (int c = 0; c < 2; ++c)
                    *(uint2*)&sth[(s * 16 + l15) * 136 + h * 32 + c * 16 + quad * 4] =
                        ovh[h][s][c];
        bf16x8 Ah0[4], Ah1[4];
        #pragma unroll
        for (int kf = 0; kf < 4; ++kf) {
            Ah0[kf] = *(const bf16x8*)&sth[l15 * 136 + kf * 32 + quad * 8];
            Ah1[kf] = *(const bf16x8*)&sth[(16 + l15) * 136 + kf * 32 + quad * 8];
        }
        #pragma unroll
        for (int h = 0; h < 4; ++h)
            #pragma unroll
            for (int s = 0; s < 2; ++s)
                #pragma unroll
                for (int c = 0; c < 2; ++c)
                    *(uint2*)&sth[(s * 16 + l15) * 136 + h * 32 + c * 16 + quad * 4] =
                        ovl[h][s][c];
        bf16x8 Al0[4], Al1[4];
        #pragma unroll
        for (int kf = 0; kf < 4; ++kf) {
            Al0[kf] = *(const bf16x8*)&sth[l15 * 136 + kf * 32 + quad * 8];
            Al1[kf] = *(const bf16x8*)&sth[(16 + l15) * 136 + kf * 32 + quad * 8];
        }

        const __bf16* __restrict__ Bh = wph + (size_t)4 * 16384;
        const __bf16* __restrict__ Bl = wpl + (size_t)4 * 16384;
        #pragma unroll
        for (int n = 0; n < 8; ++n) {
            acc0[n] = (f32x4){0.f, 0.f, 0.f, 0.f};
            acc1[n] = (f32x4){0.f, 0.f, 0.f, 0.f};
        }
        #pragma unroll
        for (int kf = 0; kf < 4; ++kf)
            #pragma unroll
            for (int n = 0; n < 8; ++n) {
                size_t boff = (size_t)((n * 4 + kf) * 64 + lane) * 8;
                bf16x8 bh = *(const bf16x8*)&Bh[boff];
                bf16x8 bl = *(const bf16x8*)&Bl[boff];
                acc0[n] = mfma16(Ah0[kf], bh, acc0[n]);
                acc0[n] = mfma16(Ah0[kf], bl, acc0[n]);
                acc0[n] = mfma16(Al0[kf], bh, acc0[n]);
                acc1[n] = mfma16(Ah1[kf], bh, acc1[n]);
                acc1[n] = mfma16(Ah1[kf], bl, acc1[n]);
                acc1[n] = mfma16(Al1[kf], bh, acc1[n]);
            }

        const size_t rbase = (size_t)m * NRES + w * 32;
        #pragma unroll
        for (int n = 0; n < 8; ++n) {
            float b = bo[n * 16 + l15];
            #pragma unroll
            for (int r = 0; r < 4; ++r) {
                out[(rbase + quad * 4 + r) * CCH + n * 16 + l15] = acc0[n][r] + b;
                out[(rbase + 16 + quad * 4 + r) * CCH + n * 16 + l15] = acc1[n][r] + b;
            }
        }
    }
}

extern "C" void kernel_launch(void* const* d_in, const int* in_sizes, int n_in,
                              void* d_out, int out_size, void* d_ws, size_t ws_size,
                              hipStream_t stream)
{
    const float* act  = (const float*)d_in[0];
    const float* mask = (const float*)d_in[1];
    const float* ln_g = (const float*)d_in[2];
    const float* ln_b = (const float*)d_in[3];
    const float* wq   = (const float*)d_in[4];
    const float* wk   = (const float*)d_in[5];
    const float* wv   = (const float*)d_in[6];
    const float* w2d  = (const float*)d_in[7];
    const float* wg   = (const float*)d_in[8];
    const float* bg   = (const float*)d_in[9];
    const float* wo   = (const float*)d_in[10];
    const float* bo   = (const float*)d_in[11];
    float* out = (float*)d_out;

    float* nbP = (float*)d_ws;                 // 4*NROWS floats = 1 MB
    __bf16* wph = (__bf16*)(nbP + 4 * NROWS);  // 5*16384 bf16
    __bf16* wpl = wph + 5 * 16384;

    prep_kernel<<<40, 256, 0, stream>>>(wq, wk, wv, wg, wo, wph, wpl);

    void* kargs[] = {
        (void*)&act, (void*)&ln_g, (void*)&ln_b, (void*)&w2d,
        (void*)&wph, (void*)&wpl, (void*)&bg, (void*)&mask,
        (void*)&nbP, (void*)&bo, (void*)&out
    };
    hipLaunchCooperativeKernel((void*)mega_kernel, dim3(256), dim3(512),
                               kargs, 0, stream);
}

// Round 6
// 193.550 us; speedup vs baseline: 1.3971x; 1.3971x over previous
//
#include <hip/hip_runtime.h>
#include <hip/hip_fp16.h>
#include <math.h>

// TriangleAttentionStartingNode: B=1, N=256, C=128, H=4, AC=32, fp32 in/out.
// R6:  precision-lite pipeline (bf16 q/k/v/P, fp16 g, hi/lo out-GEMM).
// R7:  FAILED - forced VGPR cap -> spills.
// R8:  WIN  - zero-barrier lnproj (wave-private LDS planes).
// R9:  FAILED - thinner per-wave work -> slower.
// R10: WIN(204->194) - full fusion; mega=122.8us @ 2 waves/SIMD, ~70% stall
//      on the dependent QK->exp->PV chain.
// R11: FAILED(270) - cooperative launch: in-kernel sum improved (158+3 vs
//      186) but hipLaunchCooperativeKernel costs ~110us in this harness.
// R12: (a) 16-wave mega (1024 thr): wave=16 rows, LDS 158.7KB, 1 block/CU
//      but 4 waves/SIMD (2x TLP on the stall-bound chain);
//      (b) prep merged into nb kernel -> 2 dispatches total;
//      (c) exp2 refactor: log2e folded into q-scale/nbP/biasrow (and the
//      -4 offset into biasrow) -> softmax chain = add,add,v_exp only.

#define NRES 256
#define CCH  128
#define NROWS (NRES * NRES)          // 65536
#define FACTOR 0.17677669529663687f  // 1/sqrt(32)
#define LOG2E  1.44269504088896341f

typedef __attribute__((ext_vector_type(8))) __bf16 bf16x8;
typedef __attribute__((ext_vector_type(4))) float f32x4;

__device__ __forceinline__ f32x4 mfma16(bf16x8 a, bf16x8 b, f32x4 c) {
    return __builtin_amdgcn_mfma_f32_16x16x32_bf16(a, b, c, 0, 0, 0);
}

union PK4 { __bf16 b[4]; uint2 u2; };

__device__ __forceinline__ void hilo(float x, __bf16& h, __bf16& l) {
    h = (__bf16)x;
    l = (__bf16)(x - (float)h);
}

// ------------- dispatch 1: nb (blocks 0-511) + weight prep (512-551) -------
__global__ __launch_bounds__(256) void nbprep_kernel(
    const float* __restrict__ act, const float* __restrict__ ln_g,
    const float* __restrict__ ln_b, const float* __restrict__ w2d,
    const float* __restrict__ wq, const float* __restrict__ wk,
    const float* __restrict__ wv, const float* __restrict__ wg,
    const float* __restrict__ wo,
    __bf16* __restrict__ wph, __bf16* __restrict__ wpl,
    float* __restrict__ nbP)
{
    const int t = threadIdx.x;
    if (blockIdx.x >= 512) {
        // ---- weight prep: pack into B-frag layout; q scaled by F*log2e ----
        const int gid = (blockIdx.x - 512) * 256 + t;   // 0..10239
        const int wid = gid >> 11;
        const int rem = gid & 2047;
        const int nstrip = rem >> 8;
        const int kf = (rem >> 6) & 3;
        const int lane = rem & 63;
        const int l15 = lane & 15, quad = lane >> 4;
        const float* W = (wid == 0) ? wq : (wid == 1) ? wk :
                         (wid == 2) ? wv : (wid == 3) ? wg : wo;
        const float scale = (wid == 0) ? FACTOR * LOG2E : 1.0f;
        bf16x8 hb, lb;
        #pragma unroll
        for (int e = 0; e < 8; ++e) {
            int k = kf * 32 + quad * 8 + e;
            int n = nstrip * 16 + l15;
            float v = W[k * CCH + n] * scale;
            __bf16 h, l; hilo(v, h, l);
            hb[e] = h; lb[e] = l;
        }
        *(bf16x8*)&wph[(size_t)gid * 8] = hb;
        *(bf16x8*)&wpl[(size_t)gid * 8] = lb;
        return;
    }
    // ---- nb: LN + w2d dot, scaled by log2e ----
    const int w = t >> 6, lane = t & 63;
    const int r0w = blockIdx.x * 128 + w * 32;
    const int row = lane >> 1, half = lane & 1;
    const int grow = r0w + row;
    const float* __restrict__ xp = act + (size_t)grow * CCH + half * 64;
    float4 x4[16];
    #pragma unroll
    for (int c = 0; c < 16; ++c) x4[c] = *(const float4*)(xp + c * 4);
    float s = 0.f, sq = 0.f;
    #pragma unroll
    for (int c = 0; c < 16; ++c) {
        s  += (x4[c].x + x4[c].y) + (x4[c].z + x4[c].w);
        sq += x4[c].x * x4[c].x + x4[c].y * x4[c].y +
              x4[c].z * x4[c].z + x4[c].w * x4[c].w;
    }
    s  += __shfl_xor(s, 1, 64);
    sq += __shfl_xor(sq, 1, 64);
    float mu  = s * (1.0f / CCH);
    float var = fmaf(sq, 1.0f / CCH, -mu * mu);
    float rs  = rsqrtf(var + 1e-5f);
    float nb[4] = {0.f, 0.f, 0.f, 0.f};
    const float4* __restrict__ w2d4 = (const float4*)w2d;
    #pragma unroll
    for (int c = 0; c < 16; ++c) {
        float4 g4 = *(const float4*)&ln_g[half * 64 + c * 4];
        float4 b4 = *(const float4*)&ln_b[half * 64 + c * 4];
        float* xv = (float*)&x4[c];
        float* gv = (float*)&g4;
        float* bv = (float*)&b4;
        #pragma unroll
        for (int e = 0; e < 4; ++e) {
            float av = fmaf((xv[e] - mu) * rs, gv[e], bv[e]);
            float4 wv = w2d4[half * 64 + c * 4 + e];
            nb[0] = fmaf(av, wv.x, nb[0]);
            nb[1] = fmaf(av, wv.y, nb[1]);
            nb[2] = fmaf(av, wv.z, nb[2]);
            nb[3] = fmaf(av, wv.w, nb[3]);
        }
    }
    #pragma unroll
    for (int hh = 0; hh < 4; ++hh)
        nb[hh] += __shfl_xor(nb[hh], 1, 64);
    if (half == 0) {
        const int i = grow >> 8, j = grow & 255;
        #pragma unroll
        for (int hh = 0; hh < 4; ++hh) {
            size_t f = ((size_t)hh << 14) + ((size_t)(i >> 4) << 10) +
                       ((size_t)(j >> 4) << 6) + ((size_t)((j >> 2) & 3) << 4) +
                       (i & 15);
            nbP[f * 4 + (j & 3)] = nb[hh] * LOG2E;
        }
    }
}

// ---------------- projection helper: 16 rows x 128 out-ch -----------------
__device__ __forceinline__ void proj16(const bf16x8* A0,
    const __bf16* __restrict__ Bh, int lane, f32x4* acc)
{
    #pragma unroll
    for (int n = 0; n < 8; ++n) acc[n] = (f32x4){0.f, 0.f, 0.f, 0.f};
    #pragma unroll
    for (int kf = 0; kf < 4; ++kf)
        #pragma unroll
        for (int n = 0; n < 8; ++n) {
            bf16x8 bh = *(const bf16x8*)&Bh[(size_t)((n * 4 + kf) * 64 + lane) * 8];
            acc[n] = mfma16(A0[kf], bh, acc[n]);
        }
}

// ---------------- mega kernel: 16 waves, wave = 16 rows -------------------
// One block per pair-row m, 1024 threads (16 waves, 4/SIMD).
// LDS: [0)      K / wave planes: 16 x [16][136] bf16 = 69632 B (K[256][136])
//      [69632)  V^T [128][264] bf16                  = 67584 B
//      [137216) p-buffers 16 x [16][40] bf16         = 20480 B
//      [157696) biasrow [256] f32                    =  1024 B  tot 158720
__global__ __launch_bounds__(1024) void mega_kernel(
    const float* __restrict__ act, const float* __restrict__ ln_g,
    const float* __restrict__ ln_b, const __bf16* __restrict__ wph,
    const __bf16* __restrict__ wpl, const float* __restrict__ bg,
    const float* __restrict__ mask, const float* __restrict__ nbP,
    const float* __restrict__ bo, float* __restrict__ out)
{
    __shared__ __align__(16) char smem[158720];
    const int t = threadIdx.x, w = t >> 6, lane = t & 63;
    const int l15 = lane & 15, quad = lane >> 4;
    const int m = blockIdx.x;
    __bf16* const Kl = (__bf16*)smem;                        // [256][136]
    __bf16* const aH = (__bf16*)(smem + w * 4352);           // plane w [16][136]
    __bf16* const VT = (__bf16*)(smem + 69632);              // [128][264]
    __bf16* const ph = (__bf16*)(smem + 137216 + w * 1280);  // [16][40]
    float*  const biasrow = (float*)(smem + 157696);         // [256]

    // mask bias with log2e and the -4 exp-offset folded in
    if (t < 256)
        biasrow[t] = fmaf(1.442695e9f, mask[m * NRES + t] - 1.0f, -4.0f * LOG2E);

    // ---- Phase A: LN of this wave's 16 rows -> own plane (4 lanes/row) ----
    {
        const int row = lane >> 2, g = lane & 3;   // 16 rows, 32 ch per lane
        const int grow = m * NRES + w * 16 + row;
        const float* __restrict__ xp = act + (size_t)grow * CCH + g * 32;
        float4 x4[8];
        #pragma unroll
        for (int c = 0; c < 8; ++c) x4[c] = *(const float4*)(xp + c * 4);
        float s = 0.f, sq = 0.f;
        #pragma unroll
        for (int c = 0; c < 8; ++c) {
            s  += (x4[c].x + x4[c].y) + (x4[c].z + x4[c].w);
            sq += x4[c].x * x4[c].x + x4[c].y * x4[c].y +
                  x4[c].z * x4[c].z + x4[c].w * x4[c].w;
        }
        #pragma unroll
        for (int o = 1; o <= 2; o <<= 1) {
            s  += __shfl_xor(s, o, 64);
            sq += __shfl_xor(sq, o, 64);
        }
        float mu  = s * (1.0f / CCH);
        float var = fmaf(sq, 1.0f / CCH, -mu * mu);
        float rs  = rsqrtf(var + 1e-5f);
        #pragma unroll
        for (int c2 = 0; c2 < 4; ++c2) {
            bf16x8 pk;
            #pragma unroll
            for (int cc = 0; cc < 2; ++cc) {
                const int c = c2 * 2 + cc;
                float4 g4 = *(const float4*)&ln_g[g * 32 + c * 4];
                float4 b4 = *(const float4*)&ln_b[g * 32 + c * 4];
                float* xv = (float*)&x4[c];
                float* gv = (float*)&g4;
                float* bv = (float*)&b4;
                #pragma unroll
                for (int e = 0; e < 4; ++e)
                    pk[cc * 4 + e] = (__bf16)fmaf((xv[e] - mu) * rs, gv[e], bv[e]);
            }
            *(bf16x8*)&aH[row * 136 + g * 32 + c2 * 8] = pk;
        }
    }

    // ---- A-frags to regs (same-wave LDS dep); plane then recyclable ----
    bf16x8 A0[4];
    #pragma unroll
    for (int kf = 0; kf < 4; ++kf)
        A0[kf] = *(const bf16x8*)&aH[l15 * 136 + kf * 32 + quad * 8];

    f32x4 acc[8];
    bf16x8 Qh[4];             // [head] B-frag of own q rows
    uint2  greg[4][2];        // [head][c] 4 fp16 gate vals

    // ---- q: project (pre-scaled by FACTOR*log2e), restage, hoist ----
    proj16(A0, wph, lane, acc);
    {
        __bf16* const sth = aH;
        #pragma unroll
        for (int n = 0; n < 8; ++n)
            #pragma unroll
            for (int r = 0; r < 4; ++r)
                sth[(quad * 4 + r) * 136 + n * 16 + l15] = (__bf16)acc[n][r];
        #pragma unroll
        for (int h = 0; h < 4; ++h)
            Qh[h] = *(const bf16x8*)&sth[l15 * 136 + h * 32 + quad * 8];
    }

    // ---- g: project + bias + sigmoid (fp16), restage, hoist ----
    proj16(A0, wph + 3 * 16384, lane, acc);
    {
        __half* const sthH = (__half*)aH;
        #pragma unroll
        for (int n = 0; n < 8; ++n)
            #pragma unroll
            for (int r = 0; r < 4; ++r) {
                float v = acc[n][r] + bg[n * 16 + l15];
                sthH[(quad * 4 + r) * 136 + n * 16 + l15] =
                    (__half)(1.0f / (1.0f + __expf(-v)));
            }
        #pragma unroll
        for (int h = 0; h < 4; ++h)
            #pragma unroll
            for (int c = 0; c < 2; ++c)
                greg[h][c] =
                    *(const uint2*)&sthH[l15 * 136 + h * 32 + c * 16 + quad * 4];
    }

    // ---- k: project into own plane (plane row = K row w*16+..) ----
    proj16(A0, wph + 1 * 16384, lane, acc);
    #pragma unroll
    for (int n = 0; n < 8; ++n)
        #pragma unroll
        for (int r = 0; r < 4; ++r)
            aH[(quad * 4 + r) * 136 + n * 16 + l15] = (__bf16)acc[n][r];

    // ---- v: project, scatter into V^T ----
    proj16(A0, wph + 2 * 16384, lane, acc);
    #pragma unroll
    for (int n = 0; n < 8; ++n)
        #pragma unroll
        for (int r = 0; r < 4; ++r)
            VT[(n * 16 + l15) * 264 + w * 16 + quad * 4 + r] = (__bf16)acc[n][r];

    __syncthreads();   // K/VT/biasrow ready block-wide

    // ---- attention: 4 heads, own 16 q-rows, sweep all 256 j ----
    uint2 ovh[4][2], ovl[4][2];
    #pragma unroll
    for (int h = 0; h < 4; ++h) {
        f32x4 O[2];
        O[0] = (f32x4){0.f, 0.f, 0.f, 0.f};
        O[1] = (f32x4){0.f, 0.f, 0.f, 0.f};
        float ls = 0.f;
        // 1-deep nbP prefetch (nbP pre-scaled by log2e)
        float4 nb_a[2], nb_b[2];
        #pragma unroll
        for (int js = 0; js < 2; ++js)
            nb_a[js] = *(const float4*)&nbP[
                ((size_t)h * 16384 + (size_t)w * 1024 +
                 (size_t)js * 64 + quad * 16 + l15) * 4];
        #pragma unroll 1
        for (int jb = 0; jb < NRES; jb += 32) {
            bf16x8 Kh[2];
            #pragma unroll
            for (int js = 0; js < 2; ++js)
                Kh[js] = *(const bf16x8*)&Kl[(jb + js * 16 + l15) * 136 +
                                             h * 32 + quad * 8];
            bf16x8 Vh2[2];
            #pragma unroll
            for (int c = 0; c < 2; ++c)
                Vh2[c] = *(const bf16x8*)&VT[(h * 32 + c * 16 + l15) * 264 +
                                             jb + quad * 8];
            const int jn = (jb + 32 < NRES) ? (jb >> 4) + 2 : 0;
            #pragma unroll
            for (int js = 0; js < 2; ++js)
                nb_b[js] = *(const float4*)&nbP[
                    ((size_t)h * 16384 + (size_t)w * 1024 +
                     (size_t)(jn + js) * 64 + quad * 16 + l15) * 4];
            #pragma unroll
            for (int js = 0; js < 2; ++js) {
                f32x4 S = (f32x4){0.f, 0.f, 0.f, 0.f};
                S = mfma16(Kh[js], Qh[h], S);
                float4 nb4 = nb_a[js];
                float4 mb4 = *(const float4*)&biasrow[jb + js * 16 + quad * 4];
                float p0 = exp2f(S[0] + nb4.x + mb4.x);
                float p1 = exp2f(S[1] + nb4.y + mb4.y);
                float p2 = exp2f(S[2] + nb4.z + mb4.z);
                float p3 = exp2f(S[3] + nb4.w + mb4.w);
                ls += (p0 + p1) + (p2 + p3);
                PK4 hh;
                hh.b[0] = (__bf16)p0; hh.b[1] = (__bf16)p1;
                hh.b[2] = (__bf16)p2; hh.b[3] = (__bf16)p3;
                *(uint2*)&ph[l15 * 40 + js * 16 + quad * 4] = hh.u2;
            }
            bf16x8 Ph = *(const bf16x8*)&ph[l15 * 40 + quad * 8];
            #pragma unroll
            for (int c = 0; c < 2; ++c)
                O[c] = mfma16(Vh2[c], Ph, O[c]);
            nb_a[0] = nb_b[0];
            nb_a[1] = nb_b[1];
        }
        ls += __shfl_xor(ls, 16, 64);
        ls += __shfl_xor(ls, 32, 64);
        float inv = 1.0f / ls;
        #pragma unroll
        for (int c = 0; c < 2; ++c) {
            const __half* gh = (const __half*)&greg[h][c];
            PK4 hh, lo;
            #pragma unroll
            for (int r = 0; r < 4; ++r) {
                float v = O[c][r] * inv * (float)gh[r];
                __bf16 hb; __bf16 lb; hilo(v, hb, lb);
                hh.b[r] = hb; lo.b[r] = lb;
            }
            ovh[h][c] = hh.u2;
            ovl[h][c] = lo.u2;
        }
    }
    __syncthreads();   // K/VT/p dead for all waves

    // ---- out GEMM: restage hi/lo through own plane, 3-term split MFMA ----
    {
        __bf16* const sth = aH;
        #pragma unroll
        for (int h = 0; h < 4; ++h)
            #pragma unroll
            for (int c = 0; c < 2; ++c)
                *(uint2*)&sth[l15 * 136 + h * 32 + c * 16 + quad * 4] = ovh[h][c];
        bf16x8 Ah0[4];
        #pragma unroll
        for (int kf = 0; kf < 4; ++kf)
            Ah0[kf] = *(const bf16x8*)&sth[l15 * 136 + kf * 32 + quad * 8];
        #pragma unroll
        for (int h = 0; h < 4; ++h)
            #pragma unroll
            for (int c = 0; c < 2; ++c)
                *(uint2*)&sth[l15 * 136 + h * 32 + c * 16 + quad * 4] = ovl[h][c];
        bf16x8 Al0[4];
        #pragma unroll
        for (int kf = 0; kf < 4; ++kf)
            Al0[kf] = *(const bf16x8*)&sth[l15 * 136 + kf * 32 + quad * 8];

        const __bf16* __restrict__ Bh = wph + (size_t)4 * 16384;
        const __bf16* __restrict__ Bl = wpl + (size_t)4 * 16384;
        #pragma unroll
        for (int n = 0; n < 8; ++n) acc[n] = (f32x4){0.f, 0.f, 0.f, 0.f};
        #pragma unroll
        for (int kf = 0; kf < 4; ++kf)
            #pragma unroll
            for (int n = 0; n < 8; ++n) {
                size_t boff = (size_t)((n * 4 + kf) * 64 + lane) * 8;
                bf16x8 bh = *(const bf16x8*)&Bh[boff];
                bf16x8 bl = *(const bf16x8*)&Bl[boff];
                acc[n] = mfma16(Ah0[kf], bh, acc[n]);
                acc[n] = mfma16(Ah0[kf], bl, acc[n]);
                acc[n] = mfma16(Al0[kf], bh, acc[n]);
            }

        const size_t rbase = (size_t)m * NRES + w * 16;
        #pragma unroll
        for (int n = 0; n < 8; ++n) {
            float b = bo[n * 16 + l15];
            #pragma unroll
            for (int r = 0; r < 4; ++r)
                out[(rbase + quad * 4 + r) * CCH + n * 16 + l15] = acc[n][r] + b;
        }
    }
}

extern "C" void kernel_launch(void* const* d_in, const int* in_sizes, int n_in,
                              void* d_out, int out_size, void* d_ws, size_t ws_size,
                              hipStream_t stream)
{
    const float* act  = (const float*)d_in[0];
    const float* mask = (const float*)d_in[1];
    const float* ln_g = (const float*)d_in[2];
    const float* ln_b = (const float*)d_in[3];
    const float* wq   = (const float*)d_in[4];
    const float* wk   = (const float*)d_in[5];
    const float* wv   = (const float*)d_in[6];
    const float* w2d  = (const float*)d_in[7];
    const float* wg   = (const float*)d_in[8];
    const float* bg   = (const float*)d_in[9];
    const float* wo   = (const float*)d_in[10];
    const float* bo   = (const float*)d_in[11];
    float* out = (float*)d_out;

    float* nbP = (float*)d_ws;                 // 4*NROWS floats = 1 MB
    __bf16* wph = (__bf16*)(nbP + 4 * NROWS);  // 5*16384 bf16
    __bf16* wpl = wph + 5 * 16384;

    nbprep_kernel<<<552, 256, 0, stream>>>(
        act, ln_g, ln_b, w2d, wq, wk, wv, wg, wo, wph, wpl, nbP);
    mega_kernel<<<256, 1024, 0, stream>>>(
        act, ln_g, ln_b, wph, wpl, bg, mask, nbP, bo, out);
}

// Round 7
// 189.039 us; speedup vs baseline: 1.4305x; 1.0239x over previous
//
#include <hip/hip_runtime.h>
#include <hip/hip_fp16.h>
#include <math.h>

// TriangleAttentionStartingNode: B=1, N=256, C=128, H=4, AC=32, fp32 in/out.
// R6:  precision-lite pipeline (bf16 q/k/v/P, fp16 g, hi/lo out-GEMM).
// R7:  FAILED - forced VGPR cap -> spills.
// R8:  WIN  - zero-barrier lnproj (wave-private LDS planes).
// R9:  FAILED - thinner per-wave work -> slower.
// R10: WIN(204->194) - full fusion; mega 122.8us.
// R11: FAILED(270) - cooperative launch = ~110us harness overhead.
// R12: WIN - 16-wave mega (4 waves/SIMD): 122.8->93.5us, occ 22->40%.
//      But nbprep ~90us by subtraction; mega VALU 35.6% = 4x static count
//      (64-bit addr chains + scalar b16 LDS scatters suspected).
// R13: (a) pre_kernel @2048 blocks computes LN ONCE -> aLN bf16[65536][128]
//      (+nbP +weight prep tail blocks); (b) mega LN phase deleted - A-frags
//      are 4 direct global bf16x8 loads from aLN (row-major = A-frag
//      layout); (c) inner-loop nbP addressing 32-bit; (d) V^T writes packed
//      r->consecutive-j as ds_write_b64 (32->8 LDS ops/thread).

#define NRES 256
#define CCH  128
#define NROWS (NRES * NRES)          // 65536
#define FACTOR 0.17677669529663687f  // 1/sqrt(32)
#define LOG2E  1.44269504088896341f

typedef __attribute__((ext_vector_type(8))) __bf16 bf16x8;
typedef __attribute__((ext_vector_type(4))) float f32x4;

__device__ __forceinline__ f32x4 mfma16(bf16x8 a, bf16x8 b, f32x4 c) {
    return __builtin_amdgcn_mfma_f32_16x16x32_bf16(a, b, c, 0, 0, 0);
}

union PK4 { __bf16 b[4]; uint2 u2; };

__device__ __forceinline__ void hilo(float x, __bf16& h, __bf16& l) {
    h = (__bf16)x;
    l = (__bf16)(x - (float)h);
}

// ---- dispatch 1: LN->aLN + nb (blocks 0-2047) + weight prep (2048-2087) ----
__global__ __launch_bounds__(256) void pre_kernel(
    const float* __restrict__ act, const float* __restrict__ ln_g,
    const float* __restrict__ ln_b, const float* __restrict__ w2d,
    const float* __restrict__ wq, const float* __restrict__ wk,
    const float* __restrict__ wv, const float* __restrict__ wg,
    const float* __restrict__ wo,
    __bf16* __restrict__ wph, __bf16* __restrict__ wpl,
    float* __restrict__ nbP, __bf16* __restrict__ aLN)
{
    const int t = threadIdx.x;
    if (blockIdx.x >= 2048) {
        // ---- weight prep: pack into B-frag layout; q scaled by F*log2e ----
        const int gid = (blockIdx.x - 2048) * 256 + t;   // 0..10239
        const int wid = gid >> 11;
        const int rem = gid & 2047;
        const int nstrip = rem >> 8;
        const int kf = (rem >> 6) & 3;
        const int lane = rem & 63;
        const int l15 = lane & 15, quad = lane >> 4;
        const float* W = (wid == 0) ? wq : (wid == 1) ? wk :
                         (wid == 2) ? wv : (wid == 3) ? wg : wo;
        const float scale = (wid == 0) ? FACTOR * LOG2E : 1.0f;
        bf16x8 hb, lb;
        #pragma unroll
        for (int e = 0; e < 8; ++e) {
            int k = kf * 32 + quad * 8 + e;
            int n = nstrip * 16 + l15;
            float v = W[k * CCH + n] * scale;
            __bf16 h, l; hilo(v, h, l);
            hb[e] = h; lb[e] = l;
        }
        *(bf16x8*)&wph[(size_t)gid * 8] = hb;
        *(bf16x8*)&wpl[(size_t)gid * 8] = lb;
        return;
    }
    // ---- LN once: aLN (bf16) + nb (fp32 dot, log2e-folded) ----
    const int ridx = t >> 3, g = t & 7;          // 32 rows/block, 8 thr/row
    const int grow = blockIdx.x * 32 + ridx;
    const float* __restrict__ xp = act + (size_t)grow * CCH + g * 16;
    float4 x4[4];
    #pragma unroll
    for (int c = 0; c < 4; ++c) x4[c] = *(const float4*)(xp + c * 4);
    float s = 0.f, sq = 0.f;
    #pragma unroll
    for (int c = 0; c < 4; ++c) {
        s  += (x4[c].x + x4[c].y) + (x4[c].z + x4[c].w);
        sq += x4[c].x * x4[c].x + x4[c].y * x4[c].y +
              x4[c].z * x4[c].z + x4[c].w * x4[c].w;
    }
    #pragma unroll
    for (int o = 1; o <= 4; o <<= 1) {
        s  += __shfl_xor(s, o, 64);
        sq += __shfl_xor(sq, o, 64);
    }
    float mu  = s * (1.0f / CCH);
    float var = fmaf(sq, 1.0f / CCH, -mu * mu);
    float rs  = rsqrtf(var + 1e-5f);
    float av[16];
    #pragma unroll
    for (int c = 0; c < 4; ++c) {
        float4 g4 = *(const float4*)&ln_g[g * 16 + c * 4];
        float4 b4 = *(const float4*)&ln_b[g * 16 + c * 4];
        float* xv = (float*)&x4[c];
        float* gv = (float*)&g4;
        float* bv = (float*)&b4;
        #pragma unroll
        for (int e = 0; e < 4; ++e)
            av[c * 4 + e] = fmaf((xv[e] - mu) * rs, gv[e], bv[e]);
    }
    bf16x8 o1, o2;
    #pragma unroll
    for (int e = 0; e < 8; ++e) {
        o1[e] = (__bf16)av[e];
        o2[e] = (__bf16)av[8 + e];
    }
    *(bf16x8*)&aLN[(size_t)grow * CCH + g * 16] = o1;
    *(bf16x8*)&aLN[(size_t)grow * CCH + g * 16 + 8] = o2;

    float nb[4] = {0.f, 0.f, 0.f, 0.f};
    const float4* __restrict__ w2d4 = (const float4*)w2d;
    #pragma unroll
    for (int c = 0; c < 16; ++c) {
        float4 wv = w2d4[g * 16 + c];
        nb[0] = fmaf(av[c], wv.x, nb[0]);
        nb[1] = fmaf(av[c], wv.y, nb[1]);
        nb[2] = fmaf(av[c], wv.z, nb[2]);
        nb[3] = fmaf(av[c], wv.w, nb[3]);
    }
    #pragma unroll
    for (int o = 1; o <= 4; o <<= 1)
        #pragma unroll
        for (int hh = 0; hh < 4; ++hh)
            nb[hh] += __shfl_xor(nb[hh], o, 64);
    if (g == 0) {
        const int i = grow >> 8, j = grow & 255;
        #pragma unroll
        for (int hh = 0; hh < 4; ++hh) {
            size_t f = ((size_t)hh << 14) + ((size_t)(i >> 4) << 10) +
                       ((size_t)(j >> 4) << 6) + ((size_t)((j >> 2) & 3) << 4) +
                       (i & 15);
            nbP[f * 4 + (j & 3)] = nb[hh] * LOG2E;
        }
    }
}

// ---------------- projection helper: 16 rows x 128 out-ch -----------------
__device__ __forceinline__ void proj16(const bf16x8* A0,
    const __bf16* __restrict__ Bh, int lane, f32x4* acc)
{
    #pragma unroll
    for (int n = 0; n < 8; ++n) acc[n] = (f32x4){0.f, 0.f, 0.f, 0.f};
    #pragma unroll
    for (int kf = 0; kf < 4; ++kf)
        #pragma unroll
        for (int n = 0; n < 8; ++n) {
            bf16x8 bh = *(const bf16x8*)&Bh[(size_t)((n * 4 + kf) * 64 + lane) * 8];
            acc[n] = mfma16(A0[kf], bh, acc[n]);
        }
}

// ---------------- mega kernel: 16 waves, wave = 16 rows -------------------
// One block per pair-row m, 1024 threads (16 waves, 4/SIMD).
// LDS: [0)      K / wave planes: 16 x [16][136] bf16 = 69632 B (K[256][136])
//      [69632)  V^T [128][264] bf16                  = 67584 B
//      [137216) p-buffers 16 x [16][40] bf16         = 20480 B
//      [157696) biasrow [256] f32                    =  1024 B  tot 158720
__global__ __launch_bounds__(1024) void mega_kernel(
    const __bf16* __restrict__ aLN, const __bf16* __restrict__ wph,
    const __bf16* __restrict__ wpl, const float* __restrict__ bg,
    const float* __restrict__ mask, const float* __restrict__ nbP,
    const float* __restrict__ bo, float* __restrict__ out)
{
    __shared__ __align__(16) char smem[158720];
    const int t = threadIdx.x, w = t >> 6, lane = t & 63;
    const int l15 = lane & 15, quad = lane >> 4;
    const int m = blockIdx.x;
    __bf16* const Kl = (__bf16*)smem;                        // [256][136]
    __bf16* const aH = (__bf16*)(smem + w * 4352);           // plane w [16][136]
    __bf16* const VT = (__bf16*)(smem + 69632);              // [128][264]
    __bf16* const ph = (__bf16*)(smem + 137216 + w * 1280);  // [16][40]
    float*  const biasrow = (float*)(smem + 157696);         // [256]

    // mask bias with log2e and the -4 exp-offset folded in
    if (t < 256)
        biasrow[t] = fmaf(1.442695e9f, mask[m * NRES + t] - 1.0f, -4.0f * LOG2E);

    // ---- A-frags: 4 direct global bf16x8 loads (aLN row-major) ----
    bf16x8 A0[4];
    {
        const __bf16* __restrict__ ap =
            aLN + ((size_t)m * NRES + w * 16 + l15) * CCH;
        #pragma unroll
        for (int kf = 0; kf < 4; ++kf)
            A0[kf] = *(const bf16x8*)&ap[kf * 32 + quad * 8];
    }

    f32x4 acc[8];
    bf16x8 Qh[4];             // [head] B-frag of own q rows
    uint2  greg[4][2];        // [head][c] 4 fp16 gate vals

    // ---- q: project (pre-scaled by FACTOR*log2e), restage, hoist ----
    proj16(A0, wph, lane, acc);
    {
        __bf16* const sth = aH;
        #pragma unroll
        for (int n = 0; n < 8; ++n)
            #pragma unroll
            for (int r = 0; r < 4; ++r)
                sth[(quad * 4 + r) * 136 + n * 16 + l15] = (__bf16)acc[n][r];
        #pragma unroll
        for (int h = 0; h < 4; ++h)
            Qh[h] = *(const bf16x8*)&sth[l15 * 136 + h * 32 + quad * 8];
    }

    // ---- g: project + bias + sigmoid (fp16), restage, hoist ----
    proj16(A0, wph + 3 * 16384, lane, acc);
    {
        __half* const sthH = (__half*)aH;
        #pragma unroll
        for (int n = 0; n < 8; ++n)
            #pragma unroll
            for (int r = 0; r < 4; ++r) {
                float v = acc[n][r] + bg[n * 16 + l15];
                sthH[(quad * 4 + r) * 136 + n * 16 + l15] =
                    (__half)(1.0f / (1.0f + __expf(-v)));
            }
        #pragma unroll
        for (int h = 0; h < 4; ++h)
            #pragma unroll
            for (int c = 0; c < 2; ++c)
                greg[h][c] =
                    *(const uint2*)&sthH[l15 * 136 + h * 32 + c * 16 + quad * 4];
    }

    // ---- k: project into own plane (plane row = K row w*16+..) ----
    proj16(A0, wph + 1 * 16384, lane, acc);
    #pragma unroll
    for (int n = 0; n < 8; ++n)
        #pragma unroll
        for (int r = 0; r < 4; ++r)
            aH[(quad * 4 + r) * 136 + n * 16 + l15] = (__bf16)acc[n][r];

    // ---- v: project, packed transpose-write into V^T (b64 per n) ----
    proj16(A0, wph + 2 * 16384, lane, acc);
    {
        const int jcol = w * 16 + quad * 4;
        #pragma unroll
        for (int n = 0; n < 8; ++n) {
            PK4 pv;
            #pragma unroll
            for (int r = 0; r < 4; ++r) pv.b[r] = (__bf16)acc[n][r];
            *(uint2*)&VT[(n * 16 + l15) * 264 + jcol] = pv.u2;
        }
    }

    __syncthreads();   // K/VT/biasrow ready block-wide

    // ---- attention: 4 heads, own 16 q-rows, sweep all 256 j ----
    uint2 ovh[4][2], ovl[4][2];
    #pragma unroll
    for (int h = 0; h < 4; ++h) {
        f32x4 O[2];
        O[0] = (f32x4){0.f, 0.f, 0.f, 0.f};
        O[1] = (f32x4){0.f, 0.f, 0.f, 0.f};
        float ls = 0.f;
        // 32-bit nbP addressing; 1-deep prefetch (nbP pre-scaled by log2e)
        const int nbbase = (h * 16384 + w * 1024 + quad * 16 + l15) * 4;
        float4 nb_a[2], nb_b[2];
        #pragma unroll
        for (int js = 0; js < 2; ++js)
            nb_a[js] = *(const float4*)(nbP + nbbase + (js << 8));
        #pragma unroll 1
        for (int jb = 0; jb < NRES; jb += 32) {
            bf16x8 Kh[2];
            #pragma unroll
            for (int js = 0; js < 2; ++js)
                Kh[js] = *(const bf16x8*)&Kl[(jb + js * 16 + l15) * 136 +
                                             h * 32 + quad * 8];
            bf16x8 Vh2[2];
            #pragma unroll
            for (int c = 0; c < 2; ++c)
                Vh2[c] = *(const bf16x8*)&VT[(h * 32 + c * 16 + l15) * 264 +
                                             jb + quad * 8];
            const int jn = (jb + 32 < NRES) ? (jb >> 4) + 2 : 0;
            #pragma unroll
            for (int js = 0; js < 2; ++js)
                nb_b[js] = *(const float4*)(nbP + nbbase + ((jn + js) << 8));
            #pragma unroll
            for (int js = 0; js < 2; ++js) {
                f32x4 S = (f32x4){0.f, 0.f, 0.f, 0.f};
                S = mfma16(Kh[js], Qh[h], S);
                float4 nb4 = nb_a[js];
                float4 mb4 = *(const float4*)&biasrow[jb + js * 16 + quad * 4];
                float p0 = exp2f(S[0] + nb4.x + mb4.x);
                float p1 = exp2f(S[1] + nb4.y + mb4.y);
                float p2 = exp2f(S[2] + nb4.z + mb4.z);
                float p3 = exp2f(S[3] + nb4.w + mb4.w);
                ls += (p0 + p1) + (p2 + p3);
                PK4 hh;
                hh.b[0] = (__bf16)p0; hh.b[1] = (__bf16)p1;
                hh.b[2] = (__bf16)p2; hh.b[3] = (__bf16)p3;
                *(uint2*)&ph[l15 * 40 + js * 16 + quad * 4] = hh.u2;
            }
            bf16x8 Ph = *(const bf16x8*)&ph[l15 * 40 + quad * 8];
            #pragma unroll
            for (int c = 0; c < 2; ++c)
                O[c] = mfma16(Vh2[c], Ph, O[c]);
            nb_a[0] = nb_b[0];
            nb_a[1] = nb_b[1];
        }
        ls += __shfl_xor(ls, 16, 64);
        ls += __shfl_xor(ls, 32, 64);
        float inv = 1.0f / ls;
        #pragma unroll
        for (int c = 0; c < 2; ++c) {
            const __half* gh = (const __half*)&greg[h][c];
            PK4 hh, lo;
            #pragma unroll
            for (int r = 0; r < 4; ++r) {
                float v = O[c][r] * inv * (float)gh[r];
                __bf16 hb; __bf16 lb; hilo(v, hb, lb);
                hh.b[r] = hb; lo.b[r] = lb;
            }
            ovh[h][c] = hh.u2;
            ovl[h][c] = lo.u2;
        }
    }
    __syncthreads();   // K/VT/p dead for all waves

    // ---- out GEMM: restage hi/lo through own plane, 3-term split MFMA ----
    {
        __bf16* const sth = aH;
        #pragma unroll
        for (int h = 0; h < 4; ++h)
            #pragma unroll
            for (int c = 0; c < 2; ++c)
                *(uint2*)&sth[l15 * 136 + h * 32 + c * 16 + quad * 4] = ovh[h][c];
        bf16x8 Ah0[4];
        #pragma unroll
        for (int kf = 0; kf < 4; ++kf)
            Ah0[kf] = *(const bf16x8*)&sth[l15 * 136 + kf * 32 + quad * 8];
        #pragma unroll
        for (int h = 0; h < 4; ++h)
            #pragma unroll
            for (int c = 0; c < 2; ++c)
                *(uint2*)&sth[l15 * 136 + h * 32 + c * 16 + quad * 4] = ovl[h][c];
        bf16x8 Al0[4];
        #pragma unroll
        for (int kf = 0; kf < 4; ++kf)
            Al0[kf] = *(const bf16x8*)&sth[l15 * 136 + kf * 32 + quad * 8];

        const __bf16* __restrict__ Bh = wph + (size_t)4 * 16384;
        const __bf16* __restrict__ Bl = wpl + (size_t)4 * 16384;
        #pragma unroll
        for (int n = 0; n < 8; ++n) acc[n] = (f32x4){0.f, 0.f, 0.f, 0.f};
        #pragma unroll
        for (int kf = 0; kf < 4; ++kf)
            #pragma unroll
            for (int n = 0; n < 8; ++n) {
                size_t boff = (size_t)((n * 4 + kf) * 64 + lane) * 8;
                bf16x8 bh = *(const bf16x8*)&Bh[boff];
                bf16x8 bl = *(const bf16x8*)&Bl[boff];
                acc[n] = mfma16(Ah0[kf], bh, acc[n]);
                acc[n] = mfma16(Ah0[kf], bl, acc[n]);
                acc[n] = mfma16(Al0[kf], bh, acc[n]);
            }

        const size_t rbase = (size_t)m * NRES + w * 16;
        #pragma unroll
        for (int n = 0; n < 8; ++n) {
            float b = bo[n * 16 + l15];
            #pragma unroll
            for (int r = 0; r < 4; ++r)
                out[(rbase + quad * 4 + r) * CCH + n * 16 + l15] = acc[n][r] + b;
        }
    }
}

extern "C" void kernel_launch(void* const* d_in, const int* in_sizes, int n_in,
                              void* d_out, int out_size, void* d_ws, size_t ws_size,
                              hipStream_t stream)
{
    const float* act  = (const float*)d_in[0];
    const float* mask = (const float*)d_in[1];
    const float* ln_g = (const float*)d_in[2];
    const float* ln_b = (const float*)d_in[3];
    const float* wq   = (const float*)d_in[4];
    const float* wk   = (const float*)d_in[5];
    const float* wv   = (const float*)d_in[6];
    const float* w2d  = (const float*)d_in[7];
    const float* wg   = (const float*)d_in[8];
    const float* bg   = (const float*)d_in[9];
    const float* wo   = (const float*)d_in[10];
    const float* bo   = (const float*)d_in[11];
    float* out = (float*)d_out;

    float* nbP = (float*)d_ws;                 // 4*NROWS floats = 1 MB
    __bf16* wph = (__bf16*)(nbP + 4 * NROWS);  // 5*16384 bf16
    __bf16* wpl = wph + 5 * 16384;             // 5*16384 bf16
    __bf16* aLN = wpl + 5 * 16384;             // NROWS*128 bf16 = 16 MB

    pre_kernel<<<2088, 256, 0, stream>>>(
        act, ln_g, ln_b, w2d, wq, wk, wv, wg, wo, wph, wpl, nbP, aLN);
    mega_kernel<<<256, 1024, 0, stream>>>(
        aLN, wph, wpl, bg, mask, nbP, bo, out);
}

// Round 9
// 185.071 us; speedup vs baseline: 1.4611x; 1.0214x over previous
//
#include <hip/hip_runtime.h>
#include <hip/hip_fp16.h>
#include <math.h>

// TriangleAttentionStartingNode: B=1, N=256, C=128, H=4, AC=32, fp32 in/out.
// R6:  precision-lite pipeline (bf16 q/k/v/P, fp16 g, hi/lo out-GEMM).
// R8:  WIN  - zero-barrier lnproj (wave-private LDS planes).
// R10: WIN(204->194) - full fusion; mega 122.8us.
// R11: FAILED(270) - cooperative launch = ~110us harness overhead.
// R12: WIN - 16-wave mega (4 waves/SIMD): 122.8->93.5us.
// R13: small WIN - LN hoisted to pre (aLN bf16), mega 89us.
// R14: FAILED correctness - redist() selected hi/lo on the SOURCE lane
//      before __shfl (target quad>=2 read js=0 data from quad<2 lanes).
//      Correct redist = 8 bpermute, ~neutral vs LDS roundtrip. Wrong tool.
// R15: ZERO-MOVEMENT P and epilogue via v_mfma_f32_16x16x16_bf16:
//      the 16x16 C/D layout (n=l15, q*4+r) IS the x16 B-frag layout
//      (k=quad*4+e) AND the x16 A-frag layout. So:
//      (a) PV = two K=16 MFMAs per js: S -> exp2 -> pack -> MFMA, no LDS;
//      (b) out-GEMM = 8 k-chunks of 16, A-frags = ovh/ovl directly; wo
//          packed in x16 B-frag layout by prep; restage+2nd barrier gone.

#define NRES 256
#define CCH  128
#define NROWS (NRES * NRES)          // 65536
#define FACTOR 0.17677669529663687f  // 1/sqrt(32)
#define LOG2E  1.44269504088896341f

typedef __attribute__((ext_vector_type(8))) __bf16 bf16x8;
typedef __attribute__((ext_vector_type(4))) float f32x4;
typedef __attribute__((ext_vector_type(4))) short s16x4;

__device__ __forceinline__ f32x4 mfma16(bf16x8 a, bf16x8 b, f32x4 c) {
    return __builtin_amdgcn_mfma_f32_16x16x32_bf16(a, b, c, 0, 0, 0);
}
// K=16 variant: A/B = 4 bf16 (2 VGPRs). A: m=l15, k=quad*4+e.
// B: n=l15, k=quad*4+e. D: lane holds D[m=quad*4+r][n=l15].
__device__ __forceinline__ f32x4 mfma16x16(s16x4 a, s16x4 b, f32x4 c) {
    return __builtin_amdgcn_mfma_f32_16x16x16bf16_1k(a, b, c, 0, 0, 0);
}

union PK4 { __bf16 b[4]; uint2 u2; s16x4 s4; };

__device__ __forceinline__ void hilo(float x, __bf16& h, __bf16& l) {
    h = (__bf16)x;
    l = (__bf16)(x - (float)h);
}

// ---- dispatch 1: LN->aLN + nb (blocks 0-2047) + weight prep (2048-2087) ----
__global__ __launch_bounds__(256) void pre_kernel(
    const float* __restrict__ act, const float* __restrict__ ln_g,
    const float* __restrict__ ln_b, const float* __restrict__ w2d,
    const float* __restrict__ wq, const float* __restrict__ wk,
    const float* __restrict__ wv, const float* __restrict__ wg,
    const float* __restrict__ wo,
    __bf16* __restrict__ wph, __bf16* __restrict__ wo16h,
    __bf16* __restrict__ wo16l,
    float* __restrict__ nbP, __bf16* __restrict__ aLN)
{
    const int t = threadIdx.x;
    if (blockIdx.x >= 2048) {
        const int gid = (blockIdx.x - 2048) * 256 + t;   // 0..10239
        const int wid = gid >> 11;
        const int rem = gid & 2047;
        const int lane = rem & 63;
        const int l15 = lane & 15, quad = lane >> 4;
        if (wid < 4) {
            // q/k/v/g: x32 B-frag layout (hi only); q scaled by F*log2e
            const int nstrip = rem >> 8;
            const int kf = (rem >> 6) & 3;
            const float* W = (wid == 0) ? wq : (wid == 1) ? wk :
                             (wid == 2) ? wv : wg;
            const float scale = (wid == 0) ? FACTOR * LOG2E : 1.0f;
            bf16x8 hb;
            #pragma unroll
            for (int e = 0; e < 8; ++e) {
                int k = kf * 32 + quad * 8 + e;
                int n = nstrip * 16 + l15;
                hb[e] = (__bf16)(W[k * CCH + n] * scale);
            }
            *(bf16x8*)&wph[(size_t)gid * 8] = hb;
        } else {
            // wo: x16 B-frag layout, hi/lo split.
            // frag element e <-> k = kc*16 + quad*4 + e, n = nstrip*16+l15
            const int nstrip = rem >> 8;
            const int kcp = (rem >> 6) & 3;
            #pragma unroll
            for (int sub = 0; sub < 2; ++sub) {
                const int kc = kcp * 2 + sub;
                PK4 hh, ll;
                #pragma unroll
                for (int e = 0; e < 4; ++e) {
                    int k = kc * 16 + quad * 4 + e;
                    int n = nstrip * 16 + l15;
                    __bf16 h, l; hilo(wo[k * CCH + n], h, l);
                    hh.b[e] = h; ll.b[e] = l;
                }
                const int fo = ((nstrip * 8 + kc) * 64 + lane) * 4;
                *(uint2*)&wo16h[fo] = hh.u2;
                *(uint2*)&wo16l[fo] = ll.u2;
            }
        }
        return;
    }
    // ---- LN once: aLN (bf16) + nb (fp32 dot, log2e-folded) ----
    const int ridx = t >> 3, g = t & 7;          // 32 rows/block, 8 thr/row
    const int grow = blockIdx.x * 32 + ridx;
    const float* __restrict__ xp = act + (size_t)grow * CCH + g * 16;
    float4 x4[4];
    #pragma unroll
    for (int c = 0; c < 4; ++c) x4[c] = *(const float4*)(xp + c * 4);
    float s = 0.f, sq = 0.f;
    #pragma unroll
    for (int c = 0; c < 4; ++c) {
        s  += (x4[c].x + x4[c].y) + (x4[c].z + x4[c].w);
        sq += x4[c].x * x4[c].x + x4[c].y * x4[c].y +
              x4[c].z * x4[c].z + x4[c].w * x4[c].w;
    }
    #pragma unroll
    for (int o = 1; o <= 4; o <<= 1) {
        s  += __shfl_xor(s, o, 64);
        sq += __shfl_xor(sq, o, 64);
    }
    float mu  = s * (1.0f / CCH);
    float var = fmaf(sq, 1.0f / CCH, -mu * mu);
    float rs  = rsqrtf(var + 1e-5f);
    float av[16];
    #pragma unroll
    for (int c = 0; c < 4; ++c) {
        float4 g4 = *(const float4*)&ln_g[g * 16 + c * 4];
        float4 b4 = *(const float4*)&ln_b[g * 16 + c * 4];
        float* xv = (float*)&x4[c];
        float* gv = (float*)&g4;
        float* bv = (float*)&b4;
        #pragma unroll
        for (int e = 0; e < 4; ++e)
            av[c * 4 + e] = fmaf((xv[e] - mu) * rs, gv[e], bv[e]);
    }
    bf16x8 o1, o2;
    #pragma unroll
    for (int e = 0; e < 8; ++e) {
        o1[e] = (__bf16)av[e];
        o2[e] = (__bf16)av[8 + e];
    }
    *(bf16x8*)&aLN[(size_t)grow * CCH + g * 16] = o1;
    *(bf16x8*)&aLN[(size_t)grow * CCH + g * 16 + 8] = o2;

    float nb[4] = {0.f, 0.f, 0.f, 0.f};
    const float4* __restrict__ w2d4 = (const float4*)w2d;
    #pragma unroll
    for (int c = 0; c < 16; ++c) {
        float4 wv = w2d4[g * 16 + c];
        nb[0] = fmaf(av[c], wv.x, nb[0]);
        nb[1] = fmaf(av[c], wv.y, nb[1]);
        nb[2] = fmaf(av[c], wv.z, nb[2]);
        nb[3] = fmaf(av[c], wv.w, nb[3]);
    }
    #pragma unroll
    for (int o = 1; o <= 4; o <<= 1)
        #pragma unroll
        for (int hh = 0; hh < 4; ++hh)
            nb[hh] += __shfl_xor(nb[hh], o, 64);
    if (g == 0) {
        const int i = grow >> 8, j = grow & 255;
        #pragma unroll
        for (int hh = 0; hh < 4; ++hh) {
            size_t f = ((size_t)hh << 14) + ((size_t)(i >> 4) << 10) +
                       ((size_t)(j >> 4) << 6) + ((size_t)((j >> 2) & 3) << 4) +
                       (i & 15);
            nbP[f * 4 + (j & 3)] = nb[hh] * LOG2E;
        }
    }
}

// ---------------- projection helper: 16 rows x 128 out-ch -----------------
__device__ __forceinline__ void proj16(const bf16x8* A0,
    const __bf16* __restrict__ Bh, int lane, f32x4* acc)
{
    #pragma unroll
    for (int n = 0; n < 8; ++n) acc[n] = (f32x4){0.f, 0.f, 0.f, 0.f};
    #pragma unroll
    for (int kf = 0; kf < 4; ++kf)
        #pragma unroll
        for (int n = 0; n < 8; ++n) {
            bf16x8 bh = *(const bf16x8*)&Bh[(size_t)((n * 4 + kf) * 64 + lane) * 8];
            acc[n] = mfma16(A0[kf], bh, acc[n]);
        }
}

// ---------------- mega kernel: 16 waves, wave = 16 rows -------------------
// One block per pair-row m, 1024 threads (16 waves, 4/SIMD).
// LDS: [0)      K / wave planes: 16 x [16][136] bf16 = 69632 B (K[256][136])
//      [69632)  V^T [128][264] bf16                  = 67584 B
//      [137216) biasrow [256] f32                    =  1024 B  tot 138240
__global__ __launch_bounds__(1024) void mega_kernel(
    const __bf16* __restrict__ aLN, const __bf16* __restrict__ wph,
    const __bf16* __restrict__ wo16h, const __bf16* __restrict__ wo16l,
    const float* __restrict__ bg, const float* __restrict__ mask,
    const float* __restrict__ nbP, const float* __restrict__ bo,
    float* __restrict__ out)
{
    __shared__ __align__(16) char smem[138240];
    const int t = threadIdx.x, w = t >> 6, lane = t & 63;
    const int l15 = lane & 15, quad = lane >> 4;
    const int m = blockIdx.x;
    __bf16* const Kl = (__bf16*)smem;                        // [256][136]
    __bf16* const aH = (__bf16*)(smem + w * 4352);           // plane w [16][136]
    __bf16* const VT = (__bf16*)(smem + 69632);              // [128][264]
    float*  const biasrow = (float*)(smem + 137216);         // [256]

    // mask bias with log2e and the -4 exp-offset folded in
    if (t < 256)
        biasrow[t] = fmaf(1.442695e9f, mask[m * NRES + t] - 1.0f, -4.0f * LOG2E);

    // ---- A-frags: 4 direct global bf16x8 loads (aLN row-major) ----
    bf16x8 A0[4];
    {
        const __bf16* __restrict__ ap =
            aLN + ((size_t)m * NRES + w * 16 + l15) * CCH;
        #pragma unroll
        for (int kf = 0; kf < 4; ++kf)
            A0[kf] = *(const bf16x8*)&ap[kf * 32 + quad * 8];
    }

    f32x4 acc[8];
    bf16x8 Qh[4];             // [head] B-frag of own q rows
    uint2  greg[4][2];        // [head][c] 4 fp16 gate vals

    // ---- q: project (pre-scaled by FACTOR*log2e), restage, hoist ----
    proj16(A0, wph, lane, acc);
    {
        __bf16* const sth = aH;
        #pragma unroll
        for (int n = 0; n < 8; ++n)
            #pragma unroll
            for (int r = 0; r < 4; ++r)
                sth[(quad * 4 + r) * 136 + n * 16 + l15] = (__bf16)acc[n][r];
        #pragma unroll
        for (int h = 0; h < 4; ++h)
            Qh[h] = *(const bf16x8*)&sth[l15 * 136 + h * 32 + quad * 8];
    }

    // ---- g: project + bias + sigmoid (fp16), restage, hoist ----
    proj16(A0, wph + 3 * 16384, lane, acc);
    {
        __half* const sthH = (__half*)aH;
        #pragma unroll
        for (int n = 0; n < 8; ++n)
            #pragma unroll
            for (int r = 0; r < 4; ++r) {
                float v = acc[n][r] + bg[n * 16 + l15];
                sthH[(quad * 4 + r) * 136 + n * 16 + l15] =
                    (__half)(1.0f / (1.0f + __expf(-v)));
            }
        #pragma unroll
        for (int h = 0; h < 4; ++h)
            #pragma unroll
            for (int c = 0; c < 2; ++c)
                greg[h][c] =
                    *(const uint2*)&sthH[l15 * 136 + h * 32 + c * 16 + quad * 4];
    }

    // ---- k: project into own plane (plane row = K row w*16+..) ----
    proj16(A0, wph + 1 * 16384, lane, acc);
    #pragma unroll
    for (int n = 0; n < 8; ++n)
        #pragma unroll
        for (int r = 0; r < 4; ++r)
            aH[(quad * 4 + r) * 136 + n * 16 + l15] = (__bf16)acc[n][r];

    // ---- v: project, packed transpose-write into V^T (b64 per n) ----
    proj16(A0, wph + 2 * 16384, lane, acc);
    {
        const int jcol = w * 16 + quad * 4;
        #pragma unroll
        for (int n = 0; n < 8; ++n) {
            PK4 pv;
            #pragma unroll
            for (int r = 0; r < 4; ++r) pv.b[r] = (__bf16)acc[n][r];
            *(uint2*)&VT[(n * 16 + l15) * 264 + jcol] = pv.u2;
        }
    }

    __syncthreads();   // K/VT/biasrow ready block-wide

    // ---- attention: 4 heads, own 16 q-rows, sweep all 256 j ----
    // P path is zero-movement: S (C/D layout n=l15,q*4+r) IS the x16
    // B-frag layout; V frags read as b64 in the x16 A-frag layout.
    PK4 ovh[4][2], ovl[4][2];
    #pragma unroll
    for (int h = 0; h < 4; ++h) {
        f32x4 O[2];
        O[0] = (f32x4){0.f, 0.f, 0.f, 0.f};
        O[1] = (f32x4){0.f, 0.f, 0.f, 0.f};
        float ls = 0.f;
        // 32-bit nbP addressing; 1-deep prefetch (nbP pre-scaled by log2e)
        const int nbbase = (h * 16384 + w * 1024 + quad * 16 + l15) * 4;
        float4 nb_a[2], nb_b[2];
        #pragma unroll
        for (int js = 0; js < 2; ++js)
            nb_a[js] = *(const float4*)(nbP + nbbase + (js << 8));
        #pragma unroll 1
        for (int jb = 0; jb < NRES; jb += 32) {
            bf16x8 Kh[2];
            #pragma unroll
            for (int js = 0; js < 2; ++js)
                Kh[js] = *(const bf16x8*)&Kl[(jb + js * 16 + l15) * 136 +
                                             h * 32 + quad * 8];
            // V x16 A-frags: [c][js], m=ch(l15), k=j=quad*4+e
            PK4 Vf[2][2];
            #pragma unroll
            for (int c = 0; c < 2; ++c)
                #pragma unroll
                for (int js = 0; js < 2; ++js)
                    Vf[c][js].u2 = *(const uint2*)&VT[
                        (h * 32 + c * 16 + l15) * 264 + jb + js * 16 + quad * 4];
            const int jn = (jb + 32 < NRES) ? (jb >> 4) + 2 : 0;
            #pragma unroll
            for (int js = 0; js < 2; ++js)
                nb_b[js] = *(const float4*)(nbP + nbbase + ((jn + js) << 8));
            // S for both js, exp2+pack in regs
            f32x4 S0 = (f32x4){0.f, 0.f, 0.f, 0.f};
            f32x4 S1 = (f32x4){0.f, 0.f, 0.f, 0.f};
            S0 = mfma16(Kh[0], Qh[h], S0);
            S1 = mfma16(Kh[1], Qh[h], S1);
            PK4 PJ0, PJ1;
            {
                float4 mb0 = *(const float4*)&biasrow[jb + quad * 4];
                float p0 = exp2f(S0[0] + nb_a[0].x + mb0.x);
                float p1 = exp2f(S0[1] + nb_a[0].y + mb0.y);
                float p2 = exp2f(S0[2] + nb_a[0].z + mb0.z);
                float p3 = exp2f(S0[3] + nb_a[0].w + mb0.w);
                ls += (p0 + p1) + (p2 + p3);
                PJ0.b[0] = (__bf16)p0; PJ0.b[1] = (__bf16)p1;
                PJ0.b[2] = (__bf16)p2; PJ0.b[3] = (__bf16)p3;
            }
            {
                float4 mb1 = *(const float4*)&biasrow[jb + 16 + quad * 4];
                float p0 = exp2f(S1[0] + nb_a[1].x + mb1.x);
                float p1 = exp2f(S1[1] + nb_a[1].y + mb1.y);
                float p2 = exp2f(S1[2] + nb_a[1].z + mb1.z);
                float p3 = exp2f(S1[3] + nb_a[1].w + mb1.w);
                ls += (p0 + p1) + (p2 + p3);
                PJ1.b[0] = (__bf16)p0; PJ1.b[1] = (__bf16)p1;
                PJ1.b[2] = (__bf16)p2; PJ1.b[3] = (__bf16)p3;
            }
            // PV: two K=16 MFMAs per c, P fed straight from registers
            #pragma unroll
            for (int c = 0; c < 2; ++c) {
                O[c] = mfma16x16(Vf[c][0].s4, PJ0.s4, O[c]);
                O[c] = mfma16x16(Vf[c][1].s4, PJ1.s4, O[c]);
            }
            nb_a[0] = nb_b[0];
            nb_a[1] = nb_b[1];
        }
        ls += __shfl_xor(ls, 16, 64);
        ls += __shfl_xor(ls, 32, 64);
        float inv = 1.0f / ls;
        #pragma unroll
        for (int c = 0; c < 2; ++c) {
            const __half* gh = (const __half*)&greg[h][c];
            #pragma unroll
            for (int r = 0; r < 4; ++r) {
                float v = O[c][r] * inv * (float)gh[r];
                __bf16 hb; __bf16 lb; hilo(v, hb, lb);
                ovh[h][c].b[r] = hb; ovl[h][c].b[r] = lb;
            }
        }
    }

    // ---- out GEMM: x16 MFMAs, A-frags = ovh/ovl DIRECTLY (no LDS, no
    //      barrier, no movement); B = wo16h/wo16l; 3-term split ----
    {
        #pragma unroll
        for (int n = 0; n < 8; ++n) acc[n] = (f32x4){0.f, 0.f, 0.f, 0.f};
        #pragma unroll
        for (int kc = 0; kc < 8; ++kc) {
            const int h = kc >> 1, c = kc & 1;
            s16x4 Ah = ovh[h][c].s4;
            s16x4 Al = ovl[h][c].s4;
            #pragma unroll
            for (int n = 0; n < 8; ++n) {
                const int fo = ((n * 8 + kc) * 64 + lane) * 4;
                PK4 bh, bl;
                bh.u2 = *(const uint2*)&wo16h[fo];
                bl.u2 = *(const uint2*)&wo16l[fo];
                acc[n] = mfma16x16(Ah, bh.s4, acc[n]);
                acc[n] = mfma16x16(Ah, bl.s4, acc[n]);
                acc[n] = mfma16x16(Al, bh.s4, acc[n]);
            }
        }

        const size_t rbase = (size_t)m * NRES + w * 16;
        #pragma unroll
        for (int n = 0; n < 8; ++n) {
            float b = bo[n * 16 + l15];
            #pragma unroll
            for (int r = 0; r < 4; ++r)
                out[(rbase + quad * 4 + r) * CCH + n * 16 + l15] = acc[n][r] + b;
        }
    }
}

extern "C" void kernel_launch(void* const* d_in, const int* in_sizes, int n_in,
                              void* d_out, int out_size, void* d_ws, size_t ws_size,
                              hipStream_t stream)
{
    const float* act  = (const float*)d_in[0];
    const float* mask = (const float*)d_in[1];
    const float* ln_g = (const float*)d_in[2];
    const float* ln_b = (const float*)d_in[3];
    const float* wq   = (const float*)d_in[4];
    const float* wk   = (const float*)d_in[5];
    const float* wv   = (const float*)d_in[6];
    const float* w2d  = (const float*)d_in[7];
    const float* wg   = (const float*)d_in[8];
    const float* bg   = (const float*)d_in[9];
    const float* wo   = (const float*)d_in[10];
    const float* bo   = (const float*)d_in[11];
    float* out = (float*)d_out;

    float* nbP    = (float*)d_ws;                  // 4*NROWS floats = 1 MB
    __bf16* wph   = (__bf16*)(nbP + 4 * NROWS);    // 4*16384 bf16
    __bf16* wo16h = wph + 4 * 16384;               // 16384 bf16
    __bf16* wo16l = wo16h + 16384;                 // 16384 bf16
    __bf16* aLN   = wo16l + 16384;                 // NROWS*128 bf16 = 16 MB

    pre_kernel<<<2088, 256, 0, stream>>>(
        act, ln_g, ln_b, w2d, wq, wk, wv, wg, wo, wph, wo16h, wo16l, nbP, aLN);
    mega_kernel<<<256, 1024, 0, stream>>>(
        aLN, wph, wo16h, wo16l, bg, mask, nbP, bo, out);
}